// Round 21
// baseline (98.608 us; speedup 1.0000x reference)
//
#include <hip/hip_runtime.h>
#include <math.h>

#define H 512
#define W 512
#define HW (H*W)
#define NB 4
#define NC 32

// global -> LDS direct DMA, 16B per lane. LDS dest = wave-uniform base + lane*16.
__device__ __forceinline__ void gload_lds16(const void* g, void* l) {
    __builtin_amdgcn_global_load_lds((const __attribute__((address_space(1))) void*)g,
                                     (__attribute__((address_space(3))) void*)l, 16, 0, 0);
}

// ---- fused conv kernel, v7: double-buffered A (LDS-only cost), NO P tile, 1 barrier/channel.
// Per channel: barrier (A[cur] DMA drained + A[cur^1] readers done) -> issue next DMA into
// A[cur^1] -> compute entirely from A[cur] + registers (pooled rowsums R6-style).
__global__ __launch_bounds__(256) void k_whmax_sc(const float* __restrict__ color,
                                                  const float* __restrict__ wbbx,
                                                  const float* __restrict__ wscore,
                                                  const float* __restrict__ zp,
                                                  float* __restrict__ pw,
                                                  float* __restrict__ scE) {
    __shared__ float A[2][38][140];   // 2 x 21280 B; rows Y0-3..Y0+34, cols X0-4..X0+135

    const int t  = threadIdx.x;
    const int X0 = blockIdx.x * 128;
    const int Y0 = blockIdx.y * 32;
    const int b  = blockIdx.z >> 2;
    const int g  = blockIdx.z & 3;
    const int tx = t & 31, ty = t >> 5;          // thread owns 4x4 outputs at (ty*4+ol, tx*4+cc)

    // ---- channel-invariant staging coordinates (6 chunks/thread, 1330 total) ----
    size_t goff[6];
    bool   inb[6], act[6];
    #pragma unroll
    for (int k = 0; k < 6; ++k) {
        int u = t + k * 256;
        act[k] = (u < 38 * 35);
        int r = u / 35, c4 = u % 35;
        int gy = Y0 - 3 + r, gx0 = X0 - 4 + c4 * 4;
        inb[k]  = act[k] && (gy >= 0) && (gy < H) && (gx0 >= 0) && (gx0 <= W - 4);
        goff[k] = (size_t)(gy < 0 ? 0 : gy) * W + (gx0 < 0 ? 0 : gx0);
    }

    auto stage = [&](int c, int buf) {
        const float* img = color + ((size_t)b * NC + c) * HW;
        char* Abase = (char*)&A[buf][0][0];
        #pragma unroll
        for (int k = 0; k < 6; ++k) {
            if (act[k]) {
                const float* src = inb[k] ? (img + goff[k]) : zp;
                gload_lds16(src, Abase + (size_t)((t & ~63) + k * 256) * 16);
            }
        }
    };

    // pooled-column mask (conv x zero-pad) * 1/9, and pooled-row mask (conv y zero-pad)
    float cmask[8];
    #pragma unroll
    for (int j = 0; j < 8; ++j) {
        int gx = X0 + tx * 4 - 2 + j;
        cmask[j] = (gx >= 0 && gx < W) ? (1.f / 9.f) : 0.f;
    }
    bool rmask[8];
    #pragma unroll
    for (int q = 0; q < 8; ++q) {
        int gy = Y0 + ty * 4 - 2 + q;
        rmask[q] = (gy >= 0 && gy < H);
    }

    float wmx[4][4], scacc[4][4];
    #pragma unroll
    for (int ol = 0; ol < 4; ++ol)
        #pragma unroll
        for (int cc = 0; cc < 4; ++cc) { wmx[ol][cc] = -INFINITY; scacc[ol][cc] = 0.f; }

    stage(8 * g, 0);
    int cur = 0;

    for (int ci = 0; ci < 4; ++ci) {
        const int ce = 8 * g + 2 * ci;
        const int co = ce + 1;
        const float* wc   = wbbx + ce * 25;                  // uniform -> SGPR
        const float wse   = wscore[ce];
        const float wso   = wscore[co];
        const float* imgO = color + ((size_t)b * NC + co) * HW;

        // odd-channel sc: independent global loads, issue before barrier
        float4 ov[4];
        #pragma unroll
        for (int ol = 0; ol < 4; ++ol)
            ov[ol] = *(const float4*)(imgO + (size_t)(Y0 + ty * 4 + ol) * W + X0 + tx * 4);

        __syncthreads();   // A[cur] DMA drained; prev channel's readers of A[cur^1] done

        if (ci < 3) stage(ce + 2, cur ^ 1);                  // next channel flies under compute

        #pragma unroll
        for (int ol = 0; ol < 4; ++ol) {
            scacc[ol][0] = fmaf(ov[ol].x, wso, scacc[ol][0]);
            scacc[ol][1] = fmaf(ov[ol].y, wso, scacc[ol][1]);
            scacc[ol][2] = fmaf(ov[ol].z, wso, scacc[ol][2]);
            scacc[ol][3] = fmaf(ov[ol].w, wso, scacc[ol][3]);
        }

        // even-channel sc from staged tile center
        #pragma unroll
        for (int ol = 0; ol < 4; ++ol) {
            float4 v = *(const float4*)&A[cur][3 + ty * 4 + ol][4 + tx * 4];
            scacc[ol][0] = fmaf(v.x, wse, scacc[ol][0]);
            scacc[ol][1] = fmaf(v.y, wse, scacc[ol][1]);
            scacc[ol][2] = fmaf(v.z, wse, scacc[ol][2]);
            scacc[ol][3] = fmaf(v.w, wse, scacc[ol][3]);
        }

        // conv: stream 10 A rows; rolling 3x3 rowsums; pooled row feeds conv directly
        float acc[4][4];
        #pragma unroll
        for (int ol = 0; ol < 4; ++ol)
            #pragma unroll
            for (int cc = 0; cc < 4; ++cc) acc[ol][cc] = 0.f;

        float rs[3][8];
        #pragma unroll
        for (int rr = 0; rr < 10; ++rr) {
            float4 a4 = *(const float4*)&A[cur][ty * 4 + rr][tx * 4 + 0];
            float4 b4 = *(const float4*)&A[cur][ty * 4 + rr][tx * 4 + 4];
            float4 c4 = *(const float4*)&A[cur][ty * 4 + rr][tx * 4 + 8];
            float v[12] = {a4.x, a4.y, a4.z, a4.w, b4.x, b4.y, b4.z, b4.w, c4.x, c4.y, c4.z, c4.w};
            float* rsc = rs[rr % 3];
            #pragma unroll
            for (int j = 0; j < 8; ++j) rsc[j] = v[j + 1] + v[j + 2] + v[j + 3];
            if (rr >= 2) {
                const int q = rr - 2;                        // pooled row index 0..7
                float pooled[8];
                if (rmask[q]) {
                    #pragma unroll
                    for (int j = 0; j < 8; ++j)
                        pooled[j] = (rs[(rr - 2) % 3][j] + rs[(rr - 1) % 3][j] + rs[rr % 3][j]) * cmask[j];
                } else {
                    #pragma unroll
                    for (int j = 0; j < 8; ++j) pooled[j] = 0.f;
                }
                #pragma unroll
                for (int ol = 0; ol < 4; ++ol) {
                    const int ky = q - ol;                   // compile-time after unroll
                    if (ky >= 0 && ky <= 4) {
                        #pragma unroll
                        for (int cc = 0; cc < 4; ++cc) {
                            float a = acc[ol][cc];
                            #pragma unroll
                            for (int kx = 0; kx < 5; ++kx)
                                a = fmaf(pooled[cc + kx], wc[ky * 5 + kx], a);
                            acc[ol][cc] = a;
                        }
                    }
                }
            }
        }
        #pragma unroll
        for (int ol = 0; ol < 4; ++ol)
            #pragma unroll
            for (int cc = 0; cc < 4; ++cc)
                wmx[ol][cc] = fmaxf(wmx[ol][cc], acc[ol][cc]);

        cur ^= 1;
    }

    size_t off = ((size_t)g * NB + b) * HW + (size_t)(Y0 + ty * 4) * W + X0 + tx * 4;
    #pragma unroll
    for (int ol = 0; ol < 4; ++ol) {
        *(float4*)(pw  + off + (size_t)ol * W) = make_float4(wmx[ol][0], wmx[ol][1], wmx[ol][2], wmx[ol][3]);
        *(float4*)(scE + off + (size_t)ol * W) = make_float4(scacc[ol][0], scacc[ol][1], scacc[ol][2], scacc[ol][3]);
    }
}

// ---- pool pyramid, x-split into 2 halves (512 blocks = 2/CU), unchanged (R20) ----
__global__ __launch_bounds__(256) void k_poolcand(const float* __restrict__ scE,
                                                  float* __restrict__ score_map,
                                                  float* __restrict__ cand) {
    const int xh = blockIdx.x;
    const int sb = blockIdx.y;
    const int b  = blockIdx.z;
    const int t  = threadIdx.x;
    const int y0 = sb * 8;
    const int C0 = xh * 256;

    __shared__ float A[14][264];
    __shared__ float Bf[14][264];

    for (int r = 0; r < 14; ++r) {
        int gy = y0 - 3 + r;
        for (int l = t; l < 264; l += 256) {
            int gx = C0 - 4 + l;
            float v = 0.f;
            if (gy >= 0 && gy < H && gx >= 0 && gx < W) {
                size_t idx = (size_t)b * HW + (size_t)gy * W + gx;
                v = scE[idx] + scE[(size_t)NB * HW + idx]
                  + scE[(size_t)2 * NB * HW + idx] + scE[(size_t)3 * NB * HW + idx];
            }
            A[r][l] = v;
        }
    }
    __syncthreads();
    for (int r = 0; r < 14; ++r)
        for (int l = 2 + t; l < 262; l += 256)
            Bf[r][l] = A[r][l - 2] + A[r][l - 1] + A[r][l] + A[r][l + 1] + A[r][l + 2];
    __syncthreads();
    for (int r2 = 0; r2 < 10; ++r2) {
        int gy = y0 - 1 + r2;
        for (int l = 2 + t; l < 262; l += 256) {
            int gx = C0 - 4 + l;
            float s = 0.f;
            if (gy >= 0 && gy < H && gx >= 0 && gx < W) {
                #pragma unroll
                for (int d = 0; d < 5; ++d) s += Bf[r2 + d][l];
                s *= (1.f / 25.f);
            }
            A[r2][l] = s;
        }
    }
    __syncthreads();
    for (int r2 = 0; r2 < 10; ++r2)
        for (int l = 3 + t; l < 261; l += 256)
            Bf[r2][l] = A[r2][l - 1] + A[r2][l] + A[r2][l + 1];
    __syncthreads();

    float top[10];
    #pragma unroll
    for (int k = 0; k < 10; ++k) top[k] = -INFINITY;

    const int l = 4 + t;
    for (int r3 = 0; r3 < 8; ++r3) {
        float sv = (Bf[r3][l] + Bf[r3 + 1][l] + Bf[r3 + 2][l]) * (1.f / 9.f);
        score_map[(size_t)b * HW + (size_t)(y0 + r3) * W + C0 + t] = sv;
        float s = 1.f / (1.f + expf(-sv));
        if (s > top[9]) {
            top[9] = s;
            #pragma unroll
            for (int k = 9; k > 0; --k)
                if (top[k] > top[k - 1]) { float tmp = top[k - 1]; top[k - 1] = top[k]; top[k] = tmp; }
        }
    }

    __shared__ float sv_[256];
    __shared__ int   si_[256];
    __shared__ int   swin;
    int ptr = 0;
    for (int r = 0; r < 10; ++r) {
        sv_[t] = (ptr < 10) ? top[ptr] : -INFINITY;
        si_[t] = t;
        __syncthreads();
        for (int off = 128; off > 0; off >>= 1) {
            if (t < off && sv_[t + off] > sv_[t]) { sv_[t] = sv_[t + off]; si_[t] = si_[t + off]; }
            __syncthreads();
        }
        if (t == 0) { cand[(((size_t)b * 64 + sb) * 2 + xh) * 10 + r] = sv_[0]; swin = si_[0]; }
        __syncthreads();
        if (t == swin) ptr++;
        __syncthreads();
    }
}

// ---- 10th-largest over 1280: 10 rounds of parallel extract-max (R20, ~3us) ----
__global__ __launch_bounds__(256) void k_v10(const float* __restrict__ cand, float* __restrict__ v10) {
    const int b = blockIdx.x, t = threadIdx.x;
    __shared__ float c[1280];
    __shared__ float wv[4];
    __shared__ int   wi[4];
    for (int j = t; j < 1280; j += 256) c[j] = cand[b * 1280 + j];
    __syncthreads();
    for (int r = 0; r < 10; ++r) {
        float bv = -INFINITY; int bi = 0;
        #pragma unroll
        for (int k = 0; k < 5; ++k) {
            int j = t + k * 256;
            float v = c[j];
            if (v > bv) { bv = v; bi = j; }
        }
        #pragma unroll
        for (int off = 32; off > 0; off >>= 1) {
            float ovv = __shfl_down(bv, off);
            int   ovi = __shfl_down(bi, off);
            if (ovv > bv) { bv = ovv; bi = ovi; }
        }
        if ((t & 63) == 0) { wv[t >> 6] = bv; wi[t >> 6] = bi; }
        __syncthreads();
        if (t == 0) {
            float m = wv[0]; int mi = wi[0];
            #pragma unroll
            for (int w = 1; w < 4; ++w) if (wv[w] > m) { m = wv[w]; mi = wi[w]; }
            c[mi] = -INFINITY;
            if (r == 9) v10[b] = m;
        }
        __syncthreads();
    }
}

// ---- final decode; outbuf via LDS stage -> coalesced float4 stores (R20) ----
__global__ __launch_bounds__(256) void k_final(const float* __restrict__ smap,
                                               const float* __restrict__ pw,
                                               const float* __restrict__ v10,
                                               float* __restrict__ outbuf,
                                               float* __restrict__ mbuf) {
    __shared__ float st[1280];
    const int t = threadIdx.x;
    const int p = blockIdx.x * 256 + t;
    int b = p / HW, i = p % HW;
    float scv = smap[p];
    float s   = 1.f / (1.f + expf(-scv));
    float s10 = v10[b];
    bool  m   = (s >= s10 && s > 0.6f) || (s > 0.9f);
    size_t idx = (size_t)b * HW + i;
    float wmv = fmaxf(fmaxf(pw[idx], pw[(size_t)NB * HW + idx]),
                      fmaxf(pw[(size_t)2 * NB * HW + idx], pw[(size_t)3 * NB * HW + idx]));
    // reference quirk: w = channel0 (score_map), h = channel1 (wmax)
    float wv = expf(scv) * 10.f;
    float hv = expf(wmv) * 10.f;
    float xs = (float)(i & (W - 1));
    float ys = (float)(i >> 9);
    float o0 = 0.f, o1 = 0.f, o2 = 0.f, o3 = 0.f, o4 = 0.f;
    if (m) {
        o0 = s;
        o1 = floorf(xs - wv);
        o2 = floorf(ys - hv);
        o3 = ceilf(xs + wv);
        o4 = ceilf(ys + hv);
    }
    st[t * 5 + 0] = o0; st[t * 5 + 1] = o1; st[t * 5 + 2] = o2;
    st[t * 5 + 3] = o3; st[t * 5 + 4] = o4;
    mbuf[p] = m ? 1.f : 0.f;
    __syncthreads();
    float4* ob4 = (float4*)(outbuf + (size_t)blockIdx.x * 1280);
    const float4* s4 = (const float4*)st;
    ob4[t] = s4[t];
    if (t < 64) ob4[256 + t] = s4[256 + t];
}

extern "C" void kernel_launch(void* const* d_in, const int* in_sizes, int n_in,
                              void* d_out, int out_size, void* d_ws, size_t ws_size,
                              hipStream_t stream) {
    // inputs: mask (unused), color, w_bbx, w_score
    const float* color  = (const float*)d_in[1];
    const float* wbbx   = (const float*)d_in[2];
    const float* wscore = (const float*)d_in[3];

    float* out       = (float*)d_out;
    float* score_map = out;                          // 1048576
    float* outbuf    = out + 1048576;                // 5242880
    float* mbuf      = out + 1048576 + 5242880;      // 1048576

    float* ws   = (float*)d_ws;
    float* pw   = ws;                                // 4 planes x NB*HW = 16 MB
    float* scE  = ws + (size_t)4 * NB * HW;          // 4 planes x NB*HW = 16 MB
    float* cand = ws + (size_t)8 * NB * HW;          // 5120 floats
    float* v10  = cand + 5120;                       // 4
    float* zp   = cand + 8192;                       // 256 B zero page

    hipMemsetAsync(zp, 0, 256, stream);              // zero page for OOB staging chunks

    k_whmax_sc <<<dim3(4, 16, NB * 4), 256, 0, stream>>>(color, wbbx, wscore, zp, pw, scE);
    k_poolcand <<<dim3(2, 64, NB), 256, 0, stream>>>(scE, score_map, cand);
    k_v10      <<<4, 256, 0, stream>>>(cand, v10);
    k_final    <<<(NB * HW) / 256, 256, 0, stream>>>(score_map, pw, v10, outbuf, mbuf);
}

// Round 22
// 94.710 us; speedup vs baseline: 1.0412x; 1.0412x over previous
//
#include <hip/hip_runtime.h>
#include <math.h>

#define H 512
#define W 512
#define HW (H*W)
#define NB 4
#define NC 32

// global -> LDS direct DMA, 16B per lane. LDS dest = wave-uniform base + lane*16.
__device__ __forceinline__ void gload_lds16(const void* g, void* l) {
    __builtin_amdgcn_global_load_lds((const __attribute__((address_space(1))) void*)g,
                                     (__attribute__((address_space(3))) void*)l, 16, 0, 0);
}

// ---- fused conv kernel: R18/R20 structure, but 512-thread blocks (8 waves/block).
// Same 128x32 tile, 4 even channels, same LDS (40KB). Tests the blocks/CU-cap hypothesis:
// if the residency limit is blocks/CU (not waves), 512-thread blocks double waves/CU.
__global__ __launch_bounds__(512) void k_whmax_sc(const float* __restrict__ color,
                                                  const float* __restrict__ wbbx,
                                                  const float* __restrict__ wscore,
                                                  const float* __restrict__ zp,
                                                  float* __restrict__ pw,
                                                  float* __restrict__ scE) {
    __shared__ float A[38][140];   // 1330 float4, linear chunk layout
    __shared__ float P[36][136];   // 34 float4/row, linear

    const int t  = threadIdx.x;
    const int X0 = blockIdx.x * 128;
    const int Y0 = blockIdx.y * 32;
    const int b  = blockIdx.z >> 2;
    const int g  = blockIdx.z & 3;
    const int tx = t & 31, ty = t >> 5;          // ty 0..15; thread owns rows ty*2+{0,1}, cols tx*4..+3

    // ---- channel-invariant staging coordinates (3 chunks/thread, 1330 total) ----
    size_t goff[3];
    bool   inb[3], act[3];
    #pragma unroll
    for (int k = 0; k < 3; ++k) {
        int u = t + k * 512;
        act[k] = (u < 38 * 35);
        int r = u / 35, c4 = u % 35;
        int gy = Y0 - 3 + r, gx0 = X0 - 4 + c4 * 4;
        inb[k]  = act[k] && (gy >= 0) && (gy < H) && (gx0 >= 0) && (gx0 <= W - 4);
        goff[k] = (size_t)(gy < 0 ? 0 : gy) * W + (gx0 < 0 ? 0 : gx0);
    }
    char* Abase = (char*)&A[0][0];

    float wmx[2][4], scacc[2][4];
    #pragma unroll
    for (int ol = 0; ol < 2; ++ol)
        #pragma unroll
        for (int cc = 0; cc < 4; ++cc) { wmx[ol][cc] = -INFINITY; scacc[ol][cc] = 0.f; }

    for (int ci = 0; ci < 4; ++ci) {
        const int ce = 8 * g + 2 * ci;
        const int co = ce + 1;
        const float* img  = color + ((size_t)b * NC + ce) * HW;
        const float* imgO = color + ((size_t)b * NC + co) * HW;
        const float* wc   = wbbx + ce * 25;
        const float wse   = wscore[ce];
        const float wso   = wscore[co];

        // ---- stage A via direct global->LDS DMA ----
        #pragma unroll
        for (int k = 0; k < 3; ++k) {
            if (act[k]) {
                const float* src = inb[k] ? (img + goff[k]) : zp;
                void* dst = Abase + (size_t)((t & ~63) + k * 512) * 16;
                gload_lds16(src, dst);
            }
        }

        // ---- odd channel sc: direct center reads (overlap the DMA) ----
        float4 ov[2];
        #pragma unroll
        for (int ol = 0; ol < 2; ++ol)
            ov[ol] = *(const float4*)(imgO + (size_t)(Y0 + ty * 2 + ol) * W + X0 + tx * 4);
        #pragma unroll
        for (int ol = 0; ol < 2; ++ol) {
            scacc[ol][0] = fmaf(ov[ol].x, wso, scacc[ol][0]);
            scacc[ol][1] = fmaf(ov[ol].y, wso, scacc[ol][1]);
            scacc[ol][2] = fmaf(ov[ol].z, wso, scacc[ol][2]);
            scacc[ol][3] = fmaf(ov[ol].w, wso, scacc[ol][3]);
        }

        __syncthreads();   // drains DMA + prev phase3 P-readers

        // ---- even channel sc from staged tile center ----
        #pragma unroll
        for (int ol = 0; ol < 2; ++ol) {
            float4 v = *(const float4*)&A[3 + ty * 2 + ol][4 + tx * 4];
            scacc[ol][0] = fmaf(v.x, wse, scacc[ol][0]);
            scacc[ol][1] = fmaf(v.y, wse, scacc[ol][1]);
            scacc[ol][2] = fmaf(v.z, wse, scacc[ol][2]);
            scacc[ol][3] = fmaf(v.w, wse, scacc[ol][3]);
        }

        // ---- phase 2: P = box3x3(A)/9, conv zero-pad folded; 16B chunks ----
        for (int u = t; u < 36 * 34; u += 512) {
            int pr = u / 34, ch = u % 34;
            int j0 = ch * 4;
            int gyP = Y0 - 2 + pr;
            float4 pv = make_float4(0.f, 0.f, 0.f, 0.f);
            if (gyP >= 0 && gyP < H) {
                float vs[8];
                float4 a0 = *(const float4*)&A[pr + 0][j0 + 0];
                float4 b0 = *(const float4*)&A[pr + 0][j0 + 4];
                float4 a1 = *(const float4*)&A[pr + 1][j0 + 0];
                float4 b1 = *(const float4*)&A[pr + 1][j0 + 4];
                float4 a2 = *(const float4*)&A[pr + 2][j0 + 0];
                float4 b2 = *(const float4*)&A[pr + 2][j0 + 4];
                vs[0] = a0.x + a1.x + a2.x;
                vs[1] = a0.y + a1.y + a2.y;
                vs[2] = a0.z + a1.z + a2.z;
                vs[3] = a0.w + a1.w + a2.w;
                vs[4] = b0.x + b1.x + b2.x;
                vs[5] = b0.y + b1.y + b2.y;
                vs[6] = b0.z + b1.z + b2.z;
                vs[7] = b0.w + b1.w + b2.w;
                float p[4];
                #pragma unroll
                for (int jj = 0; jj < 4; ++jj) {
                    int gxP = X0 - 2 + j0 + jj;
                    float s = (vs[jj + 1] + vs[jj + 2] + vs[jj + 3]) * (1.f / 9.f);
                    p[jj] = (gxP >= 0 && gxP < W) ? s : 0.f;
                }
                pv = make_float4(p[0], p[1], p[2], p[3]);
            }
            *(float4*)&P[pr][j0] = pv;
        }
        __syncthreads();

        // ---- phase 3: conv5x5 from P (SGPR weights), 2 output rows/thread ----
        float acc[2][4];
        #pragma unroll
        for (int ol = 0; ol < 2; ++ol)
            #pragma unroll
            for (int cc = 0; cc < 4; ++cc) acc[ol][cc] = 0.f;

        #pragma unroll
        for (int pr8 = 0; pr8 < 6; ++pr8) {
            int pr = ty * 2 + pr8;                           // <= 35
            float4 q0 = *(const float4*)&P[pr][tx * 4 + 0];
            float4 q1 = *(const float4*)&P[pr][tx * 4 + 4];
            float c8[8] = {q0.x, q0.y, q0.z, q0.w, q1.x, q1.y, q1.z, q1.w};
            #pragma unroll
            for (int ol = 0; ol < 2; ++ol) {
                const int ky = pr8 - ol;
                if (ky >= 0 && ky <= 4) {                    // compile-time after unroll
                    #pragma unroll
                    for (int cc = 0; cc < 4; ++cc) {
                        float a = acc[ol][cc];
                        #pragma unroll
                        for (int kx = 0; kx < 5; ++kx)
                            a = fmaf(c8[cc + kx], wc[ky * 5 + kx], a);
                        acc[ol][cc] = a;
                    }
                }
            }
        }
        #pragma unroll
        for (int ol = 0; ol < 2; ++ol)
            #pragma unroll
            for (int cc = 0; cc < 4; ++cc)
                wmx[ol][cc] = fmaxf(wmx[ol][cc], acc[ol][cc]);
    }

    size_t off = ((size_t)g * NB + b) * HW + (size_t)(Y0 + ty * 2) * W + X0 + tx * 4;
    #pragma unroll
    for (int ol = 0; ol < 2; ++ol) {
        *(float4*)(pw  + off + (size_t)ol * W) = make_float4(wmx[ol][0], wmx[ol][1], wmx[ol][2], wmx[ol][3]);
        *(float4*)(scE + off + (size_t)ol * W) = make_float4(scacc[ol][0], scacc[ol][1], scacc[ol][2], scacc[ol][3]);
    }
}

// ---- pool pyramid, x-split into 2 halves (512 blocks = 2/CU), unchanged (R20) ----
__global__ __launch_bounds__(256) void k_poolcand(const float* __restrict__ scE,
                                                  float* __restrict__ score_map,
                                                  float* __restrict__ cand) {
    const int xh = blockIdx.x;
    const int sb = blockIdx.y;
    const int b  = blockIdx.z;
    const int t  = threadIdx.x;
    const int y0 = sb * 8;
    const int C0 = xh * 256;

    __shared__ float A[14][264];
    __shared__ float Bf[14][264];

    for (int r = 0; r < 14; ++r) {
        int gy = y0 - 3 + r;
        for (int l = t; l < 264; l += 256) {
            int gx = C0 - 4 + l;
            float v = 0.f;
            if (gy >= 0 && gy < H && gx >= 0 && gx < W) {
                size_t idx = (size_t)b * HW + (size_t)gy * W + gx;
                v = scE[idx] + scE[(size_t)NB * HW + idx]
                  + scE[(size_t)2 * NB * HW + idx] + scE[(size_t)3 * NB * HW + idx];
            }
            A[r][l] = v;
        }
    }
    __syncthreads();
    for (int r = 0; r < 14; ++r)
        for (int l = 2 + t; l < 262; l += 256)
            Bf[r][l] = A[r][l - 2] + A[r][l - 1] + A[r][l] + A[r][l + 1] + A[r][l + 2];
    __syncthreads();
    for (int r2 = 0; r2 < 10; ++r2) {
        int gy = y0 - 1 + r2;
        for (int l = 2 + t; l < 262; l += 256) {
            int gx = C0 - 4 + l;
            float s = 0.f;
            if (gy >= 0 && gy < H && gx >= 0 && gx < W) {
                #pragma unroll
                for (int d = 0; d < 5; ++d) s += Bf[r2 + d][l];
                s *= (1.f / 25.f);
            }
            A[r2][l] = s;
        }
    }
    __syncthreads();
    for (int r2 = 0; r2 < 10; ++r2)
        for (int l = 3 + t; l < 261; l += 256)
            Bf[r2][l] = A[r2][l - 1] + A[r2][l] + A[r2][l + 1];
    __syncthreads();

    float top[10];
    #pragma unroll
    for (int k = 0; k < 10; ++k) top[k] = -INFINITY;

    const int l = 4 + t;
    for (int r3 = 0; r3 < 8; ++r3) {
        float sv = (Bf[r3][l] + Bf[r3 + 1][l] + Bf[r3 + 2][l]) * (1.f / 9.f);
        score_map[(size_t)b * HW + (size_t)(y0 + r3) * W + C0 + t] = sv;
        float s = 1.f / (1.f + expf(-sv));
        if (s > top[9]) {
            top[9] = s;
            #pragma unroll
            for (int k = 9; k > 0; --k)
                if (top[k] > top[k - 1]) { float tmp = top[k - 1]; top[k - 1] = top[k]; top[k] = tmp; }
        }
    }

    __shared__ float sv_[256];
    __shared__ int   si_[256];
    __shared__ int   swin;
    int ptr = 0;
    for (int r = 0; r < 10; ++r) {
        sv_[t] = (ptr < 10) ? top[ptr] : -INFINITY;
        si_[t] = t;
        __syncthreads();
        for (int off = 128; off > 0; off >>= 1) {
            if (t < off && sv_[t + off] > sv_[t]) { sv_[t] = sv_[t + off]; si_[t] = si_[t + off]; }
            __syncthreads();
        }
        if (t == 0) { cand[(((size_t)b * 64 + sb) * 2 + xh) * 10 + r] = sv_[0]; swin = si_[0]; }
        __syncthreads();
        if (t == swin) ptr++;
        __syncthreads();
    }
}

// ---- 10th-largest over 1280: 10 rounds of parallel extract-max (R20, ~3us) ----
__global__ __launch_bounds__(256) void k_v10(const float* __restrict__ cand, float* __restrict__ v10) {
    const int b = blockIdx.x, t = threadIdx.x;
    __shared__ float c[1280];
    __shared__ float wv[4];
    __shared__ int   wi[4];
    for (int j = t; j < 1280; j += 256) c[j] = cand[b * 1280 + j];
    __syncthreads();
    for (int r = 0; r < 10; ++r) {
        float bv = -INFINITY; int bi = 0;
        #pragma unroll
        for (int k = 0; k < 5; ++k) {
            int j = t + k * 256;
            float v = c[j];
            if (v > bv) { bv = v; bi = j; }
        }
        #pragma unroll
        for (int off = 32; off > 0; off >>= 1) {
            float ovv = __shfl_down(bv, off);
            int   ovi = __shfl_down(bi, off);
            if (ovv > bv) { bv = ovv; bi = ovi; }
        }
        if ((t & 63) == 0) { wv[t >> 6] = bv; wi[t >> 6] = bi; }
        __syncthreads();
        if (t == 0) {
            float m = wv[0]; int mi = wi[0];
            #pragma unroll
            for (int w = 1; w < 4; ++w) if (wv[w] > m) { m = wv[w]; mi = wi[w]; }
            c[mi] = -INFINITY;
            if (r == 9) v10[b] = m;
        }
        __syncthreads();
    }
}

// ---- final decode; outbuf via LDS stage -> coalesced float4 stores (R20) ----
__global__ __launch_bounds__(256) void k_final(const float* __restrict__ smap,
                                               const float* __restrict__ pw,
                                               const float* __restrict__ v10,
                                               float* __restrict__ outbuf,
                                               float* __restrict__ mbuf) {
    __shared__ float st[1280];
    const int t = threadIdx.x;
    const int p = blockIdx.x * 256 + t;
    int b = p / HW, i = p % HW;
    float scv = smap[p];
    float s   = 1.f / (1.f + expf(-scv));
    float s10 = v10[b];
    bool  m   = (s >= s10 && s > 0.6f) || (s > 0.9f);
    size_t idx = (size_t)b * HW + i;
    float wmv = fmaxf(fmaxf(pw[idx], pw[(size_t)NB * HW + idx]),
                      fmaxf(pw[(size_t)2 * NB * HW + idx], pw[(size_t)3 * NB * HW + idx]));
    // reference quirk: w = channel0 (score_map), h = channel1 (wmax)
    float wv = expf(scv) * 10.f;
    float hv = expf(wmv) * 10.f;
    float xs = (float)(i & (W - 1));
    float ys = (float)(i >> 9);
    float o0 = 0.f, o1 = 0.f, o2 = 0.f, o3 = 0.f, o4 = 0.f;
    if (m) {
        o0 = s;
        o1 = floorf(xs - wv);
        o2 = floorf(ys - hv);
        o3 = ceilf(xs + wv);
        o4 = ceilf(ys + hv);
    }
    st[t * 5 + 0] = o0; st[t * 5 + 1] = o1; st[t * 5 + 2] = o2;
    st[t * 5 + 3] = o3; st[t * 5 + 4] = o4;
    mbuf[p] = m ? 1.f : 0.f;
    __syncthreads();
    float4* ob4 = (float4*)(outbuf + (size_t)blockIdx.x * 1280);
    const float4* s4 = (const float4*)st;
    ob4[t] = s4[t];
    if (t < 64) ob4[256 + t] = s4[256 + t];
}

extern "C" void kernel_launch(void* const* d_in, const int* in_sizes, int n_in,
                              void* d_out, int out_size, void* d_ws, size_t ws_size,
                              hipStream_t stream) {
    // inputs: mask (unused), color, w_bbx, w_score
    const float* color  = (const float*)d_in[1];
    const float* wbbx   = (const float*)d_in[2];
    const float* wscore = (const float*)d_in[3];

    float* out       = (float*)d_out;
    float* score_map = out;                          // 1048576
    float* outbuf    = out + 1048576;                // 5242880
    float* mbuf      = out + 1048576 + 5242880;      // 1048576

    float* ws   = (float*)d_ws;
    float* pw   = ws;                                // 4 planes x NB*HW = 16 MB
    float* scE  = ws + (size_t)4 * NB * HW;          // 4 planes x NB*HW = 16 MB
    float* cand = ws + (size_t)8 * NB * HW;          // 5120 floats
    float* v10  = cand + 5120;                       // 4
    float* zp   = cand + 8192;                       // 256 B zero page

    hipMemsetAsync(zp, 0, 256, stream);              // zero page for OOB staging chunks

    k_whmax_sc <<<dim3(4, 16, NB * 4), 512, 0, stream>>>(color, wbbx, wscore, zp, pw, scE);
    k_poolcand <<<dim3(2, 64, NB), 256, 0, stream>>>(scE, score_map, cand);
    k_v10      <<<4, 256, 0, stream>>>(cand, v10);
    k_final    <<<(NB * HW) / 256, 256, 0, stream>>>(score_map, pw, v10, outbuf, mbuf);
}

// Round 23
// 93.157 us; speedup vs baseline: 1.0585x; 1.0167x over previous
//
#include <hip/hip_runtime.h>
#include <math.h>

#define H 512
#define W 512
#define HW (H*W)
#define NB 4
#define NC 32

// global -> LDS direct DMA, 16B per lane. LDS dest = wave-uniform base + lane*16.
__device__ __forceinline__ void gload_lds16(const void* g, void* l) {
    __builtin_amdgcn_global_load_lds((const __attribute__((address_space(1))) void*)g,
                                     (__attribute__((address_space(3))) void*)l, 16, 0, 0);
}

// ---- fused conv kernel (R18/R20 structure, best measured) ----
__global__ __launch_bounds__(256) void k_whmax_sc(const float* __restrict__ color,
                                                  const float* __restrict__ wbbx,
                                                  const float* __restrict__ wscore,
                                                  const float* __restrict__ zp,
                                                  float* __restrict__ pw,
                                                  float* __restrict__ scE) {
    __shared__ float A[38][140];
    __shared__ float P[36][136];

    const int t  = threadIdx.x;
    const int X0 = blockIdx.x * 128;
    const int Y0 = blockIdx.y * 32;
    const int b  = blockIdx.z >> 2;
    const int g  = blockIdx.z & 3;
    const int tx = t & 31, ty = t >> 5;

    size_t goff[6];
    bool   inb[6], act[6];
    #pragma unroll
    for (int k = 0; k < 6; ++k) {
        int u = t + k * 256;
        act[k] = (u < 38 * 35);
        int r = u / 35, c4 = u % 35;
        int gy = Y0 - 3 + r, gx0 = X0 - 4 + c4 * 4;
        inb[k]  = act[k] && (gy >= 0) && (gy < H) && (gx0 >= 0) && (gx0 <= W - 4);
        goff[k] = (size_t)(gy < 0 ? 0 : gy) * W + (gx0 < 0 ? 0 : gx0);
    }
    char* Abase = (char*)&A[0][0];

    float wmx[4][4], scacc[4][4];
    #pragma unroll
    for (int ol = 0; ol < 4; ++ol)
        #pragma unroll
        for (int cc = 0; cc < 4; ++cc) { wmx[ol][cc] = -INFINITY; scacc[ol][cc] = 0.f; }

    for (int ci = 0; ci < 4; ++ci) {
        const int ce = 8 * g + 2 * ci;
        const int co = ce + 1;
        const float* img  = color + ((size_t)b * NC + ce) * HW;
        const float* imgO = color + ((size_t)b * NC + co) * HW;
        const float* wc   = wbbx + ce * 25;
        const float wse   = wscore[ce];
        const float wso   = wscore[co];

        #pragma unroll
        for (int k = 0; k < 6; ++k) {
            if (act[k]) {
                const float* src = inb[k] ? (img + goff[k]) : zp;
                void* dst = Abase + (size_t)((t & ~63) + k * 256) * 16;
                gload_lds16(src, dst);
            }
        }

        float4 ov[4];
        #pragma unroll
        for (int ol = 0; ol < 4; ++ol)
            ov[ol] = *(const float4*)(imgO + (size_t)(Y0 + ty * 4 + ol) * W + X0 + tx * 4);
        #pragma unroll
        for (int ol = 0; ol < 4; ++ol) {
            scacc[ol][0] = fmaf(ov[ol].x, wso, scacc[ol][0]);
            scacc[ol][1] = fmaf(ov[ol].y, wso, scacc[ol][1]);
            scacc[ol][2] = fmaf(ov[ol].z, wso, scacc[ol][2]);
            scacc[ol][3] = fmaf(ov[ol].w, wso, scacc[ol][3]);
        }

        __syncthreads();

        #pragma unroll
        for (int ol = 0; ol < 4; ++ol) {
            float4 v = *(const float4*)&A[3 + ty * 4 + ol][4 + tx * 4];
            scacc[ol][0] = fmaf(v.x, wse, scacc[ol][0]);
            scacc[ol][1] = fmaf(v.y, wse, scacc[ol][1]);
            scacc[ol][2] = fmaf(v.z, wse, scacc[ol][2]);
            scacc[ol][3] = fmaf(v.w, wse, scacc[ol][3]);
        }

        for (int u = t; u < 36 * 34; u += 256) {
            int pr = u / 34, ch = u % 34;
            int j0 = ch * 4;
            int gyP = Y0 - 2 + pr;
            float4 pv = make_float4(0.f, 0.f, 0.f, 0.f);
            if (gyP >= 0 && gyP < H) {
                float vs[8];
                float4 a0 = *(const float4*)&A[pr + 0][j0 + 0];
                float4 b0 = *(const float4*)&A[pr + 0][j0 + 4];
                float4 a1 = *(const float4*)&A[pr + 1][j0 + 0];
                float4 b1 = *(const float4*)&A[pr + 1][j0 + 4];
                float4 a2 = *(const float4*)&A[pr + 2][j0 + 0];
                float4 b2 = *(const float4*)&A[pr + 2][j0 + 4];
                vs[0] = a0.x + a1.x + a2.x;
                vs[1] = a0.y + a1.y + a2.y;
                vs[2] = a0.z + a1.z + a2.z;
                vs[3] = a0.w + a1.w + a2.w;
                vs[4] = b0.x + b1.x + b2.x;
                vs[5] = b0.y + b1.y + b2.y;
                vs[6] = b0.z + b1.z + b2.z;
                vs[7] = b0.w + b1.w + b2.w;
                float p[4];
                #pragma unroll
                for (int jj = 0; jj < 4; ++jj) {
                    int gxP = X0 - 2 + j0 + jj;
                    float s = (vs[jj + 1] + vs[jj + 2] + vs[jj + 3]) * (1.f / 9.f);
                    p[jj] = (gxP >= 0 && gxP < W) ? s : 0.f;
                }
                pv = make_float4(p[0], p[1], p[2], p[3]);
            }
            *(float4*)&P[pr][j0] = pv;
        }
        __syncthreads();

        float acc[4][4];
        #pragma unroll
        for (int ol = 0; ol < 4; ++ol)
            #pragma unroll
            for (int cc = 0; cc < 4; ++cc) acc[ol][cc] = 0.f;

        #pragma unroll
        for (int pr8 = 0; pr8 < 8; ++pr8) {
            int pr = ty * 4 + pr8;
            float4 q0 = *(const float4*)&P[pr][tx * 4 + 0];
            float4 q1 = *(const float4*)&P[pr][tx * 4 + 4];
            float c8[8] = {q0.x, q0.y, q0.z, q0.w, q1.x, q1.y, q1.z, q1.w};
            #pragma unroll
            for (int ol = 0; ol < 4; ++ol) {
                const int ky = pr8 - ol;
                if (ky >= 0 && ky <= 4) {
                    #pragma unroll
                    for (int cc = 0; cc < 4; ++cc) {
                        float a = acc[ol][cc];
                        #pragma unroll
                        for (int kx = 0; kx < 5; ++kx)
                            a = fmaf(c8[cc + kx], wc[ky * 5 + kx], a);
                        acc[ol][cc] = a;
                    }
                }
            }
        }
        #pragma unroll
        for (int ol = 0; ol < 4; ++ol)
            #pragma unroll
            for (int cc = 0; cc < 4; ++cc)
                wmx[ol][cc] = fmaxf(wmx[ol][cc], acc[ol][cc]);
    }

    size_t off = ((size_t)g * NB + b) * HW + (size_t)(Y0 + ty * 4) * W + X0 + tx * 4;
    #pragma unroll
    for (int ol = 0; ol < 4; ++ol) {
        *(float4*)(pw  + off + (size_t)ol * W) = make_float4(wmx[ol][0], wmx[ol][1], wmx[ol][2], wmx[ol][3]);
        *(float4*)(scE + off + (size_t)ol * W) = make_float4(scacc[ol][0], scacc[ol][1], scacc[ol][2], scacc[ol][3]);
    }
}

// ---- pool pyramid, x-split into 2 halves (512 blocks = 2/CU) ----
__global__ __launch_bounds__(256) void k_poolcand(const float* __restrict__ scE,
                                                  float* __restrict__ score_map,
                                                  float* __restrict__ cand) {
    const int xh = blockIdx.x;
    const int sb = blockIdx.y;
    const int b  = blockIdx.z;
    const int t  = threadIdx.x;
    const int y0 = sb * 8;
    const int C0 = xh * 256;

    __shared__ float A[14][264];
    __shared__ float Bf[14][264];

    for (int r = 0; r < 14; ++r) {
        int gy = y0 - 3 + r;
        for (int l = t; l < 264; l += 256) {
            int gx = C0 - 4 + l;
            float v = 0.f;
            if (gy >= 0 && gy < H && gx >= 0 && gx < W) {
                size_t idx = (size_t)b * HW + (size_t)gy * W + gx;
                v = scE[idx] + scE[(size_t)NB * HW + idx]
                  + scE[(size_t)2 * NB * HW + idx] + scE[(size_t)3 * NB * HW + idx];
            }
            A[r][l] = v;
        }
    }
    __syncthreads();
    for (int r = 0; r < 14; ++r)
        for (int l = 2 + t; l < 262; l += 256)
            Bf[r][l] = A[r][l - 2] + A[r][l - 1] + A[r][l] + A[r][l + 1] + A[r][l + 2];
    __syncthreads();
    for (int r2 = 0; r2 < 10; ++r2) {
        int gy = y0 - 1 + r2;
        for (int l = 2 + t; l < 262; l += 256) {
            int gx = C0 - 4 + l;
            float s = 0.f;
            if (gy >= 0 && gy < H && gx >= 0 && gx < W) {
                #pragma unroll
                for (int d = 0; d < 5; ++d) s += Bf[r2 + d][l];
                s *= (1.f / 25.f);
            }
            A[r2][l] = s;
        }
    }
    __syncthreads();
    for (int r2 = 0; r2 < 10; ++r2)
        for (int l = 3 + t; l < 261; l += 256)
            Bf[r2][l] = A[r2][l - 1] + A[r2][l] + A[r2][l + 1];
    __syncthreads();

    float top[10];
    #pragma unroll
    for (int k = 0; k < 10; ++k) top[k] = -INFINITY;

    const int l = 4 + t;
    for (int r3 = 0; r3 < 8; ++r3) {
        float sv = (Bf[r3][l] + Bf[r3 + 1][l] + Bf[r3 + 2][l]) * (1.f / 9.f);
        score_map[(size_t)b * HW + (size_t)(y0 + r3) * W + C0 + t] = sv;
        float s = 1.f / (1.f + expf(-sv));
        if (s > top[9]) {
            top[9] = s;
            #pragma unroll
            for (int k = 9; k > 0; --k)
                if (top[k] > top[k - 1]) { float tmp = top[k - 1]; top[k - 1] = top[k]; top[k] = tmp; }
        }
    }

    __shared__ float sv_[256];
    __shared__ int   si_[256];
    __shared__ int   swin;
    int ptr = 0;
    for (int r = 0; r < 10; ++r) {
        sv_[t] = (ptr < 10) ? top[ptr] : -INFINITY;
        si_[t] = t;
        __syncthreads();
        for (int off = 128; off > 0; off >>= 1) {
            if (t < off && sv_[t + off] > sv_[t]) { sv_[t] = sv_[t + off]; si_[t] = si_[t + off]; }
            __syncthreads();
        }
        if (t == 0) { cand[(((size_t)b * 64 + sb) * 2 + xh) * 10 + r] = sv_[0]; swin = si_[0]; }
        __syncthreads();
        if (t == swin) ptr++;
        __syncthreads();
    }
}

// ---- 10th-largest over 1280: 10 rounds of parallel extract-max (~3us) ----
__global__ __launch_bounds__(256) void k_v10(const float* __restrict__ cand, float* __restrict__ v10) {
    const int b = blockIdx.x, t = threadIdx.x;
    __shared__ float c[1280];
    __shared__ float wv[4];
    __shared__ int   wi[4];
    for (int j = t; j < 1280; j += 256) c[j] = cand[b * 1280 + j];
    __syncthreads();
    for (int r = 0; r < 10; ++r) {
        float bv = -INFINITY; int bi = 0;
        #pragma unroll
        for (int k = 0; k < 5; ++k) {
            int j = t + k * 256;
            float v = c[j];
            if (v > bv) { bv = v; bi = j; }
        }
        #pragma unroll
        for (int off = 32; off > 0; off >>= 1) {
            float ovv = __shfl_down(bv, off);
            int   ovi = __shfl_down(bi, off);
            if (ovv > bv) { bv = ovv; bi = ovi; }
        }
        if ((t & 63) == 0) { wv[t >> 6] = bv; wi[t >> 6] = bi; }
        __syncthreads();
        if (t == 0) {
            float m = wv[0]; int mi = wi[0];
            #pragma unroll
            for (int w = 1; w < 4; ++w) if (wv[w] > m) { m = wv[w]; mi = wi[w]; }
            c[mi] = -INFINITY;
            if (r == 9) v10[b] = m;
        }
        __syncthreads();
    }
}

// ---- final decode; outbuf via LDS stage -> coalesced float4 stores ----
__global__ __launch_bounds__(256) void k_final(const float* __restrict__ smap,
                                               const float* __restrict__ pw,
                                               const float* __restrict__ v10,
                                               float* __restrict__ outbuf,
                                               float* __restrict__ mbuf) {
    __shared__ float st[1280];
    const int t = threadIdx.x;
    const int p = blockIdx.x * 256 + t;
    int b = p / HW, i = p % HW;
    float scv = smap[p];
    float s   = 1.f / (1.f + expf(-scv));
    float s10 = v10[b];
    bool  m   = (s >= s10 && s > 0.6f) || (s > 0.9f);
    size_t idx = (size_t)b * HW + i;
    float wmv = fmaxf(fmaxf(pw[idx], pw[(size_t)NB * HW + idx]),
                      fmaxf(pw[(size_t)2 * NB * HW + idx], pw[(size_t)3 * NB * HW + idx]));
    // reference quirk: w = channel0 (score_map), h = channel1 (wmax)
    float wv = expf(scv) * 10.f;
    float hv = expf(wmv) * 10.f;
    float xs = (float)(i & (W - 1));
    float ys = (float)(i >> 9);
    float o0 = 0.f, o1 = 0.f, o2 = 0.f, o3 = 0.f, o4 = 0.f;
    if (m) {
        o0 = s;
        o1 = floorf(xs - wv);
        o2 = floorf(ys - hv);
        o3 = ceilf(xs + wv);
        o4 = ceilf(ys + hv);
    }
    st[t * 5 + 0] = o0; st[t * 5 + 1] = o1; st[t * 5 + 2] = o2;
    st[t * 5 + 3] = o3; st[t * 5 + 4] = o4;
    mbuf[p] = m ? 1.f : 0.f;
    __syncthreads();
    float4* ob4 = (float4*)(outbuf + (size_t)blockIdx.x * 1280);
    const float4* s4 = (const float4*)st;
    ob4[t] = s4[t];
    if (t < 64) ob4[256 + t] = s4[256 + t];
}

extern "C" void kernel_launch(void* const* d_in, const int* in_sizes, int n_in,
                              void* d_out, int out_size, void* d_ws, size_t ws_size,
                              hipStream_t stream) {
    // inputs: mask (unused), color, w_bbx, w_score
    const float* color  = (const float*)d_in[1];
    const float* wbbx   = (const float*)d_in[2];
    const float* wscore = (const float*)d_in[3];

    float* out       = (float*)d_out;
    float* score_map = out;                          // 1048576
    float* outbuf    = out + 1048576;                // 5242880
    float* mbuf      = out + 1048576 + 5242880;      // 1048576

    float* ws   = (float*)d_ws;
    float* pw   = ws;                                // 4 planes x NB*HW = 16 MB
    float* scE  = ws + (size_t)4 * NB * HW;          // 4 planes x NB*HW = 16 MB
    float* cand = ws + (size_t)8 * NB * HW;          // 5120 floats
    float* v10  = cand + 5120;                       // 4
    float* zp   = cand + 8192;                       // 256 B zero page

    hipMemsetAsync(zp, 0, 256, stream);              // zero page for OOB staging chunks

    k_whmax_sc <<<dim3(4, 16, NB * 4), 256, 0, stream>>>(color, wbbx, wscore, zp, pw, scE);
    k_poolcand <<<dim3(2, 64, NB), 256, 0, stream>>>(scE, score_map, cand);
    k_v10      <<<4, 256, 0, stream>>>(cand, v10);
    k_final    <<<(NB * HW) / 256, 256, 0, stream>>>(score_map, pw, v10, outbuf, mbuf);
}